// Round 3
// 738.994 us; speedup vs baseline: 1.2019x; 1.2019x over previous
//
#include <hip/hip_runtime.h>
#include <hip/hip_bf16.h>

#define D_    4096
#define KVH_  8
#define HD_   128
#define MAXS_ 4096
#define M_    256
#define NCH   8                  // kv split chunks
#define TPC   (MAXS_ / NCH)      // 512 kv positions per chunk

using frag_ab = __attribute__((ext_vector_type(8))) short;   // 8 x bf16
using frag_cd = __attribute__((ext_vector_type(4))) float;   // 4 x f32

__device__ __forceinline__ short bfb(float f) {
  union { float f; unsigned u; } cv; cv.f = f;
  unsigned u = cv.u;
  return (short)((u + 0x7fffu + ((u >> 16) & 1u)) >> 16);  // RN-even fp32->bf16
}

// ---------------- GEMM with fused f32->bf16 convert+transpose staging ----------------
// MODE 0: A = x (f32 [256][4096]); B = Wq|Wk|Wv (f32 [4096][ncols], routed by n0);
//         fused RoPE epilogue -> q_bf/k_bf/v_bf
// MODE 1: A = ctx_bf (bf16 [256][4096]); B = Wo (f32 [4096][4096]); f32 out
// 2-phase pipelined: prefetch next K-tile to regs before MFMA loop.
#define LDT 72

template<int MODE>
__global__ __launch_bounds__(256) void gemm_bf(
    const short* __restrict__ A_bf, const float* __restrict__ A_f,
    const float* __restrict__ W0, const float* __restrict__ W1,
    const float* __restrict__ W2,
    short* __restrict__ q_bf, short* __restrict__ k_bf, short* __restrict__ v_bf,
    float* __restrict__ Cf, const int* __restrict__ sp)
{
  __shared__ __align__(16) short lds_a[64 * LDT];
  __shared__ __align__(16) short lds_b[64 * LDT];
  int tid = threadIdx.x;
  int wave = tid >> 6, lane = tid & 63, quad = lane >> 4, l16 = lane & 15;
  int m0 = blockIdx.y * 64;
  int n0 = blockIdx.x * 64;

  // B source routing (n-tiles never straddle arrays: 64 | boundaries)
  const float* Wb; int ncols, col;
  if (MODE == 1)       { Wb = W0; ncols = 4096; col = n0; }
  else if (n0 < 4096)  { Wb = W0; ncols = 4096; col = n0; }
  else if (n0 < 5120)  { Wb = W1; ncols = 1024; col = n0 - 4096; }
  else                 { Wb = W2; ncols = 1024; col = n0 - 5120; }

  int tg = tid >> 4, tl = tid & 15;   // staging map: tg = k-block of 4, tl*4 = n (or k4)

  const frag_cd fz = {0.f, 0.f, 0.f, 0.f};
  frag_cd acc[4];
#pragma unroll
  for (int i = 0; i < 4; i++) acc[i] = fz;

  // prefetch registers
  float4 rb0, rb1, rb2, rb3;          // B tile: 4 row-adjacent float4 (k..k+3, n4..n4+3)
  float4 ra0, ra1, ra2, ra3;          // MODE 0 A tile
  frag_ab rabf0, rabf1;               // MODE 1 A tile

  auto loadB = [&](int kk) {
    const float* base = Wb + (size_t)(kk + tg * 4) * ncols + col + tl * 4;
    rb0 = *(const float4*)(base);
    rb1 = *(const float4*)(base + ncols);
    rb2 = *(const float4*)(base + 2 * ncols);
    rb3 = *(const float4*)(base + 3 * ncols);
  };
  auto loadA = [&](int kk) {
    if (MODE == 0) {
      const float* xb = A_f + (size_t)(m0 + tg) * 4096 + kk + tl * 4;
      ra0 = *(const float4*)(xb);
      ra1 = *(const float4*)(xb + (size_t)16 * 4096);
      ra2 = *(const float4*)(xb + (size_t)32 * 4096);
      ra3 = *(const float4*)(xb + (size_t)48 * 4096);
    } else {
      int m = tid >> 3, k8 = (tid & 7) << 3;
      rabf0 = *(const frag_ab*)(A_bf + (size_t)(m0 + m) * 4096 + kk + k8);
      rabf1 = *(const frag_ab*)(A_bf + (size_t)(m0 + 32 + m) * 4096 + kk + k8);
    }
  };
  auto storeB = [&]() {
    int kb = tg * 4, n4 = tl * 4;
    short4 s;
    s.x = bfb(rb0.x); s.y = bfb(rb1.x); s.z = bfb(rb2.x); s.w = bfb(rb3.x);
    *(short4*)(&lds_b[(n4 + 0) * LDT + kb]) = s;
    s.x = bfb(rb0.y); s.y = bfb(rb1.y); s.z = bfb(rb2.y); s.w = bfb(rb3.y);
    *(short4*)(&lds_b[(n4 + 1) * LDT + kb]) = s;
    s.x = bfb(rb0.z); s.y = bfb(rb1.z); s.z = bfb(rb2.z); s.w = bfb(rb3.z);
    *(short4*)(&lds_b[(n4 + 2) * LDT + kb]) = s;
    s.x = bfb(rb0.w); s.y = bfb(rb1.w); s.z = bfb(rb2.w); s.w = bfb(rb3.w);
    *(short4*)(&lds_b[(n4 + 3) * LDT + kb]) = s;
  };
  auto storeA = [&]() {
    if (MODE == 0) {
      int k4 = tl * 4;
      short4 s;
      s.x = bfb(ra0.x); s.y = bfb(ra0.y); s.z = bfb(ra0.z); s.w = bfb(ra0.w);
      *(short4*)(&lds_a[(0 + tg) * LDT + k4]) = s;
      s.x = bfb(ra1.x); s.y = bfb(ra1.y); s.z = bfb(ra1.z); s.w = bfb(ra1.w);
      *(short4*)(&lds_a[(16 + tg) * LDT + k4]) = s;
      s.x = bfb(ra2.x); s.y = bfb(ra2.y); s.z = bfb(ra2.z); s.w = bfb(ra2.w);
      *(short4*)(&lds_a[(32 + tg) * LDT + k4]) = s;
      s.x = bfb(ra3.x); s.y = bfb(ra3.y); s.z = bfb(ra3.z); s.w = bfb(ra3.w);
      *(short4*)(&lds_a[(48 + tg) * LDT + k4]) = s;
    } else {
      int m = tid >> 3, k8 = (tid & 7) << 3;
      *(frag_ab*)(&lds_a[m * LDT + k8]) = rabf0;
      *(frag_ab*)(&lds_a[(32 + m) * LDT + k8]) = rabf1;
    }
  };

  loadA(0); loadB(0);
  for (int kk = 0; kk < 4096; kk += 64) {
    // barrier #1: prior MFMA ds_reads consumed (conservative vmcnt drain here is
    // free: it waits exactly the prefetch the stores are about to use).
    __syncthreads();
    storeA(); storeB();
    if (kk + 64 < 4096) { loadA(kk + 64); loadB(kk + 64); }   // stays in flight across barrier
    // barrier #2: make ds_writes visible WITHOUT draining vmcnt (avoid m97 drain trap)
    asm volatile("s_waitcnt lgkmcnt(0)" ::: "memory");
    __builtin_amdgcn_s_barrier();
    __builtin_amdgcn_sched_barrier(0);   // rule #18: fence ds_reads below the barrier
#pragma unroll
    for (int k0 = 0; k0 < 64; k0 += 32) {
      frag_ab af = *(const frag_ab*)(&lds_a[(wave * 16 + l16) * LDT + k0 + quad * 8]);
#pragma unroll
      for (int nt = 0; nt < 4; nt++) {
        frag_ab bfr = *(const frag_ab*)(&lds_b[(nt * 16 + l16) * LDT + k0 + quad * 8]);
        acc[nt] = __builtin_amdgcn_mfma_f32_16x16x32_bf16(af, bfr, acc[nt], 0, 0, 0);
      }
    }
  }

  int start_pos = (MODE == 0) ? *sp : 0;
#pragma unroll
  for (int nt = 0; nt < 4; nt++) {
    int n = n0 + nt * 16 + l16;
#pragma unroll
    for (int r = 0; r < 4; r++) {
      int m = m0 + wave * 16 + quad * 4 + r;
      float v = acc[nt][r];
      if (MODE == 1) {
        Cf[(size_t)m * 4096 + n] = v;
      } else {
        float outv = v;
        if (n < 5120) {   // RoPE for q and k columns
          float partner = __shfl_xor(v, 1);
          int hd = n & (HD_ - 1);
          float theta = exp2f(-(float)(hd >> 1) * 0.2076205059304601f);  // log2(10000)/64
          float fr = (float)(start_pos + (m & 15)) * theta;
          float sn, cs;
          sincosf(fr, &sn, &cs);
          outv = v * cs + ((n & 1) ? partner * sn : -partner * sn);
        }
        short ob = bfb(outv);
        if (n < 4096)      q_bf[(size_t)m * 4096 + n] = ob;
        else if (n < 5120) k_bf[(size_t)m * 1024 + n - 4096] = ob;
        else               v_bf[(size_t)m * 1024 + n - 5120] = ob;
      }
    }
  }
}

// ---------------- flash attention, split-kv (8 chunks) ----------------
#define KLD 136   // k_s stride (2-way-free reads)
#define VLD 72    // vT stride, t-block XOR swizzled (2-way stores AND reads)
#define PLD 72

__global__ __launch_bounds__(256, 4) void attn_kernel(
    const short* __restrict__ qb,        // 256 x 4096 bf16 (rope'd)
    const short* __restrict__ kb,        // 256 x 1024 bf16 (rope'd new keys)
    const short* __restrict__ vb,        // 256 x 1024 bf16
    const float* __restrict__ cache_k,   // 16 x 4096 x 8 x 128 f32
    const float* __restrict__ cache_v,
    float* __restrict__ part_ctx,        // [1024][64][128]
    float* __restrict__ part_m,          // [1024][64]
    float* __restrict__ part_l,
    const int* __restrict__ sp)
{
  __shared__ __align__(16) short k_s[64 * KLD];   // 17408 B
  __shared__ __align__(16) short vT[HD_ * VLD];   // 18432 B
  short* p_s = k_s;                               // aliased (extra barrier guards it)

  int chunk = blockIdx.x, kvh = blockIdx.y, b = blockIdx.z;
  int tid = threadIdx.x;
  int wave = tid >> 6, lane = tid & 63, quad = lane >> 4, l16 = lane & 15;
  int start_pos = *sp;

  frag_ab qf[4];
  {
    const short* qrow = qb + (size_t)(b * 16 + l16) * D_ + (kvh * 4 + wave) * HD_;
#pragma unroll
    for (int k0 = 0; k0 < 4; k0++)
      qf[k0] = *(const frag_ab*)(qrow + k0 * 32 + quad * 8);
  }

  const frag_cd fz = {0.f, 0.f, 0.f, 0.f};
  frag_cd acc_o[8];
#pragma unroll
  for (int i = 0; i < 8; i++) acc_o[i] = fz;
  float m_i[4], l_i[4];
#pragma unroll
  for (int r = 0; r < 4; r++) { m_i[r] = -1e30f; l_i[r] = 0.f; }

  int rloc = tid >> 5;
  int lane32 = tid & 31;
  int hd4 = lane32 * 4;
  const float scale = 0.08838834764831845f;

  for (int it = 0; it < TPC / 64; it++) {
    int t0 = chunk * TPC + it * 64;
    __syncthreads();   // A: prior PV reads done
#pragma unroll
    for (int pass = 0; pass < 8; pass++) {
      int row = pass * 8 + rloc;
      int t = t0 + row;
      short4 kq, vq;
      if (t < start_pos) {
        size_t off = (((size_t)b * MAXS_ + t) * KVH_ + kvh) * HD_ + hd4;
        float4 k4 = *(const float4*)(cache_k + off);
        float4 v4 = *(const float4*)(cache_v + off);
        kq.x = bfb(k4.x); kq.y = bfb(k4.y); kq.z = bfb(k4.z); kq.w = bfb(k4.w);
        vq.x = bfb(v4.x); vq.y = bfb(v4.y); vq.z = bfb(v4.z); vq.w = bfb(v4.w);
      } else {
        int s = t - start_pos;
        size_t off = (size_t)(b * 16 + s) * (KVH_ * HD_) + kvh * HD_ + hd4;
        kq = *(const short4*)(kb + off);
        vq = *(const short4*)(vb + off);
      }
      *(short4*)(&k_s[row * KLD + hd4]) = kq;
      int cb = row >> 3, wi = row & 7;
      vT[(hd4 + 0) * VLD + (((cb ^ (((hd4 + 0) >> 3) & 7)) << 3) | wi)] = vq.x;
      vT[(hd4 + 1) * VLD + (((cb ^ (((hd4 + 1) >> 3) & 7)) << 3) | wi)] = vq.y;
      vT[(hd4 + 2) * VLD + (((cb ^ (((hd4 + 2) >> 3) & 7)) << 3) | wi)] = vq.z;
      vT[(hd4 + 3) * VLD + (((cb ^ (((hd4 + 3) >> 3) & 7)) << 3) | wi)] = vq.w;
    }
    __syncthreads();   // B: tiles staged

    frag_cd sc[4];
#pragma unroll
    for (int i = 0; i < 4; i++) sc[i] = fz;
#pragma unroll
    for (int k0 = 0; k0 < HD_; k0 += 32) {
#pragma unroll
      for (int nt = 0; nt < 4; nt++) {
        frag_ab bfm = *(const frag_ab*)(&k_s[(nt * 16 + l16) * KLD + k0 + quad * 8]);
        sc[nt] = __builtin_amdgcn_mfma_f32_16x16x32_bf16(qf[k0 >> 5], bfm, sc[nt], 0, 0, 0);
      }
    }

    float alpha[4];
#pragma unroll
    for (int r = 0; r < 4; r++) {
      float mx = fmaxf(fmaxf(sc[0][r], sc[1][r]), fmaxf(sc[2][r], sc[3][r])) * scale;
#pragma unroll
      for (int off = 1; off < 16; off <<= 1) mx = fmaxf(mx, __shfl_xor(mx, off));
      float mnew = fmaxf(m_i[r], mx);
      alpha[r] = __expf(m_i[r] - mnew);
      m_i[r] = mnew;
      float rsum = 0.f;
#pragma unroll
      for (int nt = 0; nt < 4; nt++) {
        float p = __expf(sc[nt][r] * scale - mnew);
        sc[nt][r] = p;
        rsum += p;
      }
#pragma unroll
      for (int off = 1; off < 16; off <<= 1) rsum += __shfl_xor(rsum, off);
      l_i[r] = l_i[r] * alpha[r] + rsum;
    }
#pragma unroll
    for (int nt = 0; nt < 8; nt++)
#pragma unroll
      for (int r = 0; r < 4; r++) acc_o[nt][r] *= alpha[r];

    __syncthreads();   // C: all QK reads of k_s done before p_s overwrites it
#pragma unroll
    for (int r = 0; r < 4; r++)
#pragma unroll
      for (int nt = 0; nt < 4; nt++)
        p_s[(wave * 16 + quad * 4 + r) * PLD + nt * 16 + l16] = bfb(sc[nt][r]);

#pragma unroll
    for (int k0 = 0; k0 < 64; k0 += 32) {
      frag_ab af = *(const frag_ab*)(&p_s[(wave * 16 + l16) * PLD + k0 + quad * 8]);
      int tb = (k0 >> 3) + quad;
#pragma unroll
      for (int nt = 0; nt < 8; nt++) {
        int hd = nt * 16 + l16;
        frag_ab bfm = *(const frag_ab*)(&vT[hd * VLD + ((tb ^ ((hd >> 3) & 7)) << 3)]);
        acc_o[nt] = __builtin_amdgcn_mfma_f32_16x16x32_bf16(af, bfm, acc_o[nt], 0, 0, 0);
      }
    }
  }

  int blk = ((b * 8 + kvh) << 3) + chunk;
#pragma unroll
  for (int nt = 0; nt < 8; nt++)
#pragma unroll
    for (int r = 0; r < 4; r++) {
      int qrow = wave * 16 + quad * 4 + r;
      part_ctx[((size_t)blk * 64 + qrow) * HD_ + nt * 16 + l16] = acc_o[nt][r];
    }
  if (l16 == 0) {
#pragma unroll
    for (int r = 0; r < 4; r++) {
      int qrow = wave * 16 + quad * 4 + r;
      part_m[blk * 64 + qrow] = m_i[r];
      part_l[blk * 64 + qrow] = l_i[r];
    }
  }
}

// ---------------- combine split-kv partials -> ctx bf16 ----------------
__global__ __launch_bounds__(256) void combine_kernel(
    const float* __restrict__ part_ctx, const float* __restrict__ part_m,
    const float* __restrict__ part_l, short* __restrict__ ctx_bf)
{
  int bk = blockIdx.x;            // b*8 + kvh
  int b = bk >> 3, kvh = bk & 7;
  int tid = threadIdx.x;
  __shared__ float w_s[8][64];
  __shared__ float inv_l[64];
  if (tid < 64) {
    float M = -1e30f;
#pragma unroll
    for (int c = 0; c < 8; c++) M = fmaxf(M, part_m[(bk * 8 + c) * 64 + tid]);
    float ls = 0.f;
#pragma unroll
    for (int c = 0; c < 8; c++) {
      float w = __expf(part_m[(bk * 8 + c) * 64 + tid] - M);
      w_s[c][tid] = w;
      ls += part_l[(bk * 8 + c) * 64 + tid] * w;
    }
    inv_l[tid] = 1.f / ls;
  }
  __syncthreads();
  for (int idx = tid; idx < 64 * 128; idx += 256) {
    int qrow = idx >> 7, hd = idx & 127;
    float acc = 0.f;
#pragma unroll
    for (int c = 0; c < 8; c++)
      acc += part_ctx[((size_t)(bk * 8 + c) * 64 + qrow) * HD_ + hd] * w_s[c][qrow];
    float val = acc * inv_l[qrow];
    int r = qrow >> 4, s = qrow & 15;
    ctx_bf[(size_t)(b * 16 + s) * D_ + (kvh * 4 + r) * HD_ + hd] = bfb(val);
  }
}

extern "C" void kernel_launch(void* const* d_in, const int* in_sizes, int n_in,
                              void* d_out, int out_size, void* d_ws, size_t ws_size,
                              hipStream_t stream)
{
  const float* x       = (const float*)d_in[0];
  const float* Wq      = (const float*)d_in[1];
  const float* Wk      = (const float*)d_in[2];
  const float* Wv      = (const float*)d_in[3];
  const float* Wo      = (const float*)d_in[4];
  const float* cache_k = (const float*)d_in[5];
  const float* cache_v = (const float*)d_in[6];
  const int*   sp      = (const int*)d_in[7];

  char* w = (char*)d_ws;
  auto alloc = [&](size_t bytes) { char* p = w; w += (bytes + 255) & ~(size_t)255; return p; };
  short* q_bf   = (short*)alloc((size_t)M_ * 4096 * 2);
  short* k_bf   = (short*)alloc((size_t)M_ * 1024 * 2);
  short* v_bf   = (short*)alloc((size_t)M_ * 1024 * 2);
  short* ctx_bf = (short*)alloc((size_t)M_ * 4096 * 2);
  float* part_ctx = (float*)alloc((size_t)1024 * 64 * 128 * 4);
  float* part_m   = (float*)alloc((size_t)1024 * 64 * 4);
  float* part_l   = (float*)alloc((size_t)1024 * 64 * 4);

  // QKV projection + RoPE, staging Wq/Wk/Wv f32 directly (prep kernel eliminated)
  gemm_bf<0><<<dim3(6144 / 64, M_ / 64), 256, 0, stream>>>(
      nullptr, x, Wq, Wk, Wv, q_bf, k_bf, v_bf, nullptr, sp);

  attn_kernel<<<dim3(NCH, 8, 16), 256, 0, stream>>>(
      q_bf, k_bf, v_bf, cache_k, cache_v, part_ctx, part_m, part_l, sp);

  combine_kernel<<<128, 256, 0, stream>>>(part_ctx, part_m, part_l, ctx_bf);

  // output projection, staging Wo f32 directly
  gemm_bf<1><<<dim3(4096 / 64, M_ / 64), 256, 0, stream>>>(
      ctx_bf, nullptr, Wo, nullptr, nullptr, nullptr, nullptr, nullptr, (float*)d_out, sp);
}